// Round 10
// baseline (211.083 us; speedup 1.0000x reference)
//
#include <hip/hip_runtime.h>
#include <hip/hip_bf16.h>
#include <math.h>

typedef __bf16 bf16x8 __attribute__((ext_vector_type(8)));
typedef float f32x4 __attribute__((ext_vector_type(4)));
typedef float f32x16 __attribute__((ext_vector_type(16)));

#define T_TOK 2048
#define HD 1024
#define ID 768
#define NE 16
#define NEZ 24
#define NK 4
#define SCALE_F 2.5f

#define MFMA32(a, b, c) __builtin_amdgcn_mfma_f32_32x32x16_bf16(a, b, c, 0, 0, 0)

__device__ __forceinline__ unsigned short f2bf(float f) {
  unsigned int u = __builtin_bit_cast(unsigned int, f);
  u += 0x7FFFu + ((u >> 16) & 1u);          // RNE
  return (unsigned short)(u >> 16);
}

// native casts -> v_cvt_pk_bf16_f32
__device__ __forceinline__ bf16x8 cvt8(float4 a, float4 b) {
  bf16x8 t;
  t[0] = (__bf16)a.x; t[1] = (__bf16)a.y; t[2] = (__bf16)a.z; t[3] = (__bf16)a.w;
  t[4] = (__bf16)b.x; t[5] = (__bf16)b.y; t[6] = (__bf16)b.z; t[7] = (__bf16)b.w;
  return t;
}

// async global->LDS, 16B per lane; dest linear (base + lane*16)
__device__ __forceinline__ void gload16(const void* g, void* l) {
  __builtin_amdgcn_global_load_lds(
      (const __attribute__((address_space(1))) void*)(unsigned long long)(uintptr_t)g,
      (__attribute__((address_space(3))) void*)(uintptr_t)l, 16, 0, 0);
}

// ---------------- router v3: wave-per-token, register-only ------------------
__global__ __launch_bounds__(256) void router_k(
    const float* __restrict__ x, const float* __restrict__ wr,
    const float* __restrict__ bias,
    int* __restrict__ counts, int* __restrict__ lists, float* __restrict__ wlist,
    unsigned short* __restrict__ xb, float* __restrict__ out) {
  const int wave = threadIdx.x >> 6, l = threadIdx.x & 63;
  const int t = blockIdx.x * 4 + wave;

  float4 xr[4];
#pragma unroll
  for (int c = 0; c < 4; ++c)
    xr[c] = *(const float4*)(x + (size_t)t * HD + c * 256 + l * 4);
#pragma unroll
  for (int c = 0; c < 4; ++c) {
    ushort4 h;
    h.x = f2bf(xr[c].x); h.y = f2bf(xr[c].y); h.z = f2bf(xr[c].z); h.w = f2bf(xr[c].w);
    *(ushort4*)(xb + (size_t)t * HD + c * 256 + l * 4) = h;
  }

  float acc[NEZ];
#pragma unroll 4
  for (int e = 0; e < NEZ; ++e) {
    float4 s = {0.f, 0.f, 0.f, 0.f};
#pragma unroll
    for (int c = 0; c < 4; ++c) {
      float4 w4 = *(const float4*)(wr + (size_t)e * HD + c * 256 + l * 4);
      s.x = fmaf(w4.x, xr[c].x, s.x); s.y = fmaf(w4.y, xr[c].y, s.y);
      s.z = fmaf(w4.z, xr[c].z, s.z); s.w = fmaf(w4.w, xr[c].w, s.w);
    }
    acc[e] = (s.x + s.y) + (s.z + s.w);
  }
#pragma unroll
  for (int s = 1; s < 64; s <<= 1) {
#pragma unroll
    for (int e = 0; e < NEZ; ++e) acc[e] += __shfl_xor(acc[e], s);
  }
  float sc[NEZ], scb[NEZ];
#pragma unroll
  for (int e = 0; e < NEZ; ++e) {
    float s = 1.f / (1.f + expf(-acc[e]));
    sc[e] = s;
    scb[e] = s + bias[e];
  }
  unsigned picked = 0;
  int ids[NK]; float wv[NK]; float ssum = 0.f;
#pragma unroll
  for (int k = 0; k < NK; ++k) {
    int best = 0; float bv = -1e30f; float bsc = 0.f;
#pragma unroll
    for (int e = 0; e < NEZ; ++e) {
      bool take = (((picked >> e) & 1u) == 0) && (scb[e] > bv);
      best = take ? e : best;
      bv = take ? scb[e] : bv;
      bsc = take ? sc[e] : bsc;
    }
    picked |= 1u << best;
    ids[k] = best; wv[k] = bsc; ssum += bsc;
  }
  const float inv = SCALE_F / ssum;
  float zw = 0.f;
#pragma unroll
  for (int k = 0; k < NK; ++k)
    zw += (ids[k] >= NE) ? wv[k] * inv : 0.f;
  if (l < NK) {
    int id = ids[l];
    if (id < NE) {
      int p = atomicAdd(&counts[id], 1);
      lists[id * T_TOK + p] = t;
      wlist[id * T_TOK + p] = wv[l] * inv;
    }
  }
#pragma unroll
  for (int c = 0; c < 4; ++c) {
    float4 o;
    o.x = xr[c].x * zw; o.y = xr[c].y * zw;
    o.z = xr[c].z * zw; o.w = xr[c].w * zw;
    *(float4*)(out + (size_t)t * HD + c * 256 + l * 4) = o;
  }
}

__global__ void scan_k(const int* __restrict__ counts, int* __restrict__ offs) {
  if (threadIdx.x == 0 && blockIdx.x == 0) {
    int s = 0;
    for (int e = 0; e < NE; ++e) { offs[e] = s; s += counts[e]; }
    offs[NE] = s;
  }
}

// ============================ gate/up GEMM =================================
// 256 thr / 4 waves (2M x 2N), tile 128M x 64N(g,u) x 32K, 2-phase dbuf.
// mfma_32x32x16. LDS/buf 16KB: A[128][32]bf16 @0 (gload_lds, swizzled src),
// G bf16 @8192 (4KB), U bf16 @12288 (reg-staged: f32 global->cvt->ds_write).
// T14 split: issue stage loads, comp(cur), then cvt+ds_write, barrier.
__global__ __launch_bounds__(256, 4) void gu_k(
    const unsigned short* __restrict__ xb,
    const float* __restrict__ wg, const float* __restrict__ wu,
    const int* __restrict__ counts, const int* __restrict__ offs,
    const int* __restrict__ lists, unsigned short* __restrict__ abuf) {
  const int b = blockIdx.x;
  const int L = (b & 7) * 384 + (b >> 3);   // XCD-contiguous logical id
  const int e = L / 192;
  const int rem = L % 192;
  const int xs = rem / 16, ys = rem % 16;   // ys fastest: B-panel reuse on-XCD
  const int cnt = counts[e];
  const int m0 = ys * 128;
  if (m0 >= cnt) return;
  const int n0 = xs * 64;

  __shared__ char lds[2][16384];
  const int tid = threadIdx.x;

  // A staging: 512 16B units, 2/thread; unit u -> row=u>>2, slot=u&3,
  // source chunk c=(slot-(row>>1))&3 (read slot=(c+(row>>1))&3)
  const unsigned short* asrc[2];
#pragma unroll
  for (int j = 0; j < 2; ++j) {
    int u = j * 256 + tid;
    int row = u >> 2;
    int m = m0 + row; if (m >= cnt) m = cnt - 1;
    int tok = lists[e * T_TOK + m];
    int c = ((u & 3) - (row >> 1)) & 3;
    asrc[j] = xb + (size_t)tok * HD + c * 8;
  }
  // B reg-staging source: col=tid&63, kchunk=tid>>6 (8 f32 each)
  const size_t wrow = (size_t)e * ID * HD + (size_t)(n0 + (tid & 63)) * HD + (tid >> 6) * 8;
  const float* gsrc = wg + wrow;
  const float* usrc = wu + wrow;

  const int wid = tid >> 6, l = tid & 63;
  const int wm = (wid >> 1) * 64, wn = (wid & 1) * 32;
  const int lr = l & 31, lk = l >> 5;

  // precomputed LDS read offsets (chunk = kk*2 + lk; k = chunk*8..+7)
  int aoff[2][2], boff[2];
#pragma unroll
  for (int fm = 0; fm < 2; ++fm)
#pragma unroll
    for (int kk = 0; kk < 2; ++kk) {
      int rr = wm + fm * 32 + lr;
      aoff[fm][kk] = rr * 64 + (((kk * 2 + lk) + (rr >> 1)) & 3) * 16;
    }
#pragma unroll
  for (int kk = 0; kk < 2; ++kk)
    boff[kk] = 8192 + ((kk * 2 + lk) * 64 + wn + lr) * 16;

  f32x16 ag[2] = {}; f32x16 au[2] = {};
  float4 g0, g1, u0, u1;

  auto stageA = [&](int bb, int k0) {
    char* base = &lds[bb][0];
#pragma unroll
    for (int j = 0; j < 2; ++j)
      gload16(asrc[j] + k0, base + (j * 256 + tid) * 16);
  };
  auto greadB = [&](int k0) {
    g0 = *(const float4*)(gsrc + k0);
    g1 = *(const float4*)(gsrc + k0 + 4);
    u0 = *(const float4*)(usrc + k0);
    u1 = *(const float4*)(usrc + k0 + 4);
  };
  auto writeB = [&](int bb) {
    char* base = &lds[bb][0];
    *(bf16x8*)(base + 8192 + tid * 16) = cvt8(g0, g1);
    *(bf16x8*)(base + 12288 + tid * 16) = cvt8(u0, u1);
  };
  auto comp = [&](int bb) {
    const char* base = &lds[bb][0];
#pragma unroll
    for (int kk = 0; kk < 2; ++kk) {
      bf16x8 a0 = *(const bf16x8*)(base + aoff[0][kk]);
      bf16x8 a1 = *(const bf16x8*)(base + aoff[1][kk]);
      bf16x8 bg = *(const bf16x8*)(base + boff[kk]);
      bf16x8 bu = *(const bf16x8*)(base + boff[kk] + 4096);
      ag[0] = MFMA32(a0, bg, ag[0]);
      au[0] = MFMA32(a0, bu, au[0]);
      ag[1] = MFMA32(a1, bg, ag[1]);
      au[1] = MFMA32(a1, bu, au[1]);
    }
  };

  stageA(0, 0); greadB(0); writeB(0);
  __syncthreads();
  for (int t = 0; t < 32; t += 2) {
    stageA(1, (t + 1) * 32); greadB((t + 1) * 32);   // in flight during comp
    comp(0);
    writeB(1);
    __syncthreads();
    if (t + 2 < 32) { stageA(0, (t + 2) * 32); greadB((t + 2) * 32); }
    comp(1);
    if (t + 2 < 32) writeB(0);
    __syncthreads();
  }

  const int rowbase = offs[e] + m0;
  const int col = n0 + wn + lr;                      // D: col = l&31
#pragma unroll
  for (int fm = 0; fm < 2; ++fm)
#pragma unroll
    for (int rg = 0; rg < 16; ++rg) {
      int mr = wm + fm * 32 + (rg & 3) + 8 * (rg >> 2) + 4 * lk;
      if (m0 + mr < cnt) {
        float g = ag[fm][rg], u = au[fm][rg];
        float s = 1.0f / (1.0f + expf(-g));
        abuf[(size_t)(rowbase + mr) * ID + col] = f2bf(g * s * u);
      }
    }
}

// ============================ down GEMM ====================================
// Same structure. Tile 128M x 64N x 32K, 24 steps. LDS/buf 12KB:
// A[128][32]bf16 @0, B bf16 @8192 (reg-staged from fp32 wd).
__global__ __launch_bounds__(256, 4) void dn_k(
    const unsigned short* __restrict__ abuf,
    const float* __restrict__ wd,
    const int* __restrict__ counts, const int* __restrict__ offs,
    const int* __restrict__ lists, const float* __restrict__ wlist,
    float* __restrict__ out) {
  const int b = blockIdx.x;
  const int L = (b & 7) * 512 + (b >> 3);
  const int e = L / 256;
  const int rem = L % 256;
  const int xs = rem / 16, ys = rem % 16;
  const int cnt = counts[e];
  const int m0 = ys * 128;
  if (m0 >= cnt) return;
  const int n0 = xs * 64;

  __shared__ char lds[2][12288];
  const int tid = threadIdx.x;

  const unsigned short* asrc[2];
#pragma unroll
  for (int j = 0; j < 2; ++j) {
    int u = j * 256 + tid;
    int row = u >> 2;
    int m = m0 + row; if (m >= cnt) m = cnt - 1;
    int c = ((u & 3) - (row >> 1)) & 3;
    asrc[j] = abuf + (size_t)(offs[e] + m) * ID + c * 8;
  }
  const float* bsrc = wd + (size_t)e * HD * ID + (size_t)(n0 + (tid & 63)) * ID + (tid >> 6) * 8;

  const int wid = tid >> 6, l = tid & 63;
  const int wm = (wid >> 1) * 64, wn = (wid & 1) * 32;
  const int lr = l & 31, lk = l >> 5;

  int aoff[2][2], boff[2];
#pragma unroll
  for (int fm = 0; fm < 2; ++fm)
#pragma unroll
    for (int kk = 0; kk < 2; ++kk) {
      int rr = wm + fm * 32 + lr;
      aoff[fm][kk] = rr * 64 + (((kk * 2 + lk) + (rr >> 1)) & 3) * 16;
    }
#pragma unroll
  for (int kk = 0; kk < 2; ++kk)
    boff[kk] = 8192 + ((kk * 2 + lk) * 64 + wn + lr) * 16;

  f32x16 acc[2] = {};
  float4 b0, b1;

  auto stageA = [&](int bb, int k0) {
    char* base = &lds[bb][0];
#pragma unroll
    for (int j = 0; j < 2; ++j)
      gload16(asrc[j] + k0, base + (j * 256 + tid) * 16);
  };
  auto greadB = [&](int k0) {
    b0 = *(const float4*)(bsrc + k0);
    b1 = *(const float4*)(bsrc + k0 + 4);
  };
  auto writeB = [&](int bb) {
    *(bf16x8*)(&lds[bb][0] + 8192 + tid * 16) = cvt8(b0, b1);
  };
  auto comp = [&](int bb) {
    const char* base = &lds[bb][0];
#pragma unroll
    for (int kk = 0; kk < 2; ++kk) {
      bf16x8 a0 = *(const bf16x8*)(base + aoff[0][kk]);
      bf16x8 a1 = *(const bf16x8*)(base + aoff[1][kk]);
      bf16x8 bb2 = *(const bf16x8*)(base + boff[kk]);
      acc[0] = MFMA32(a0, bb2, acc[0]);
      acc[1] = MFMA32(a1, bb2, acc[1]);
    }
  };

  stageA(0, 0); greadB(0); writeB(0);
  __syncthreads();
  for (int t = 0; t < 24; t += 2) {
    stageA(1, (t + 1) * 32); greadB((t + 1) * 32);
    comp(0);
    writeB(1);
    __syncthreads();
    if (t + 2 < 24) { stageA(0, (t + 2) * 32); greadB((t + 2) * 32); }
    comp(1);
    if (t + 2 < 24) writeB(0);
    __syncthreads();
  }

  const int col = n0 + wn + lr;
#pragma unroll
  for (int fm = 0; fm < 2; ++fm)
#pragma unroll
    for (int rg = 0; rg < 16; ++rg) {
      int mr = wm + fm * 32 + (rg & 3) + 8 * (rg >> 2) + 4 * lk;
      if (m0 + mr < cnt) {
        int tok = lists[e * T_TOK + m0 + mr];
        float wt = wlist[e * T_TOK + m0 + mr];
        atomicAdd(&out[(size_t)tok * HD + col], acc[fm][rg] * wt);
      }
    }
}

extern "C" void kernel_launch(void* const* d_in, const int* in_sizes, int n_in,
                              void* d_out, int out_size, void* d_ws, size_t ws_size,
                              hipStream_t stream) {
  (void)in_sizes; (void)n_in; (void)out_size; (void)ws_size;
  const float* x    = (const float*)d_in[0];
  const float* wr   = (const float*)d_in[3];
  const float* bias = (const float*)d_in[4];
  const float* wg   = (const float*)d_in[5];
  const float* wu   = (const float*)d_in[6];
  const float* wd   = (const float*)d_in[7];
  float* out = (float*)d_out;

  char* p = (char*)d_ws;
  auto alloc = [&](size_t bytes) {
    char* r = p;
    p += (bytes + 255) & ~(size_t)255;
    return r;
  };
  int*   counts  = (int*)alloc(NE * 4);
  int*   offs    = (int*)alloc((NE + 1) * 4);
  int*   lists   = (int*)alloc((size_t)NE * T_TOK * 4);
  float* wlist   = (float*)alloc((size_t)NE * T_TOK * 4);
  unsigned short* xb   = (unsigned short*)alloc((size_t)T_TOK * HD * 2);
  unsigned short* abuf = (unsigned short*)alloc((size_t)(T_TOK * NK + 256) * ID * 2);

  hipMemsetAsync(counts, 0, NE * 4, stream);
  router_k<<<T_TOK / 4, 256, 0, stream>>>(x, wr, bias, counts, lists, wlist, xb, out);
  scan_k<<<1, 64, 0, stream>>>(counts, offs);
  gu_k<<<3072, 256, 0, stream>>>(xb, wg, wu, counts, offs, lists, abuf);
  dn_k<<<4096, 256, 0, stream>>>(abuf, wd, counts, offs, lists, wlist, out);
}

// Round 11
// 138.328 us; speedup vs baseline: 1.5260x; 1.5260x over previous
//
#include <hip/hip_runtime.h>
#include <hip/hip_bf16.h>
#include <math.h>

typedef __bf16 bf16x8 __attribute__((ext_vector_type(8)));
typedef float f32x4 __attribute__((ext_vector_type(4)));

#define T_TOK 2048
#define HD 1024
#define ID 768
#define NE 16
#define NEZ 24
#define NK 4
#define SCALE_F 2.5f

#define MFMA(a, b, c) __builtin_amdgcn_mfma_f32_16x16x32_bf16(a, b, c, 0, 0, 0)

__device__ __forceinline__ unsigned short f2bf(float f) {
  unsigned int u = __builtin_bit_cast(unsigned int, f);
  u += 0x7FFFu + ((u >> 16) & 1u);          // RNE
  return (unsigned short)(u >> 16);
}
__device__ __forceinline__ float bf2f(unsigned short h) {
  unsigned int u = ((unsigned int)h) << 16;
  return __builtin_bit_cast(float, u);
}

// native casts -> v_cvt_pk_bf16_f32
__device__ __forceinline__ bf16x8 cvt8(float4 a, float4 b) {
  bf16x8 t;
  t[0] = (__bf16)a.x; t[1] = (__bf16)a.y; t[2] = (__bf16)a.z; t[3] = (__bf16)a.w;
  t[4] = (__bf16)b.x; t[5] = (__bf16)b.y; t[6] = (__bf16)b.z; t[7] = (__bf16)b.w;
  return t;
}

// async global->LDS, 16B per lane; dest linear (base + lane*16)
__device__ __forceinline__ void gload16(const void* g, void* l) {
  __builtin_amdgcn_global_load_lds(
      (const __attribute__((address_space(1))) void*)(unsigned long long)(uintptr_t)g,
      (__attribute__((address_space(3))) void*)(uintptr_t)l, 16, 0, 0);
}

// ---------------- router: wave-per-token, register-only ---------------------
// Emits lists (token), wlist (weight), klist (t*4+k slot), zw; xb (bf16 x).
__global__ __launch_bounds__(256) void router_k(
    const float* __restrict__ x, const float* __restrict__ wr,
    const float* __restrict__ bias,
    int* __restrict__ counts, int* __restrict__ lists, float* __restrict__ wlist,
    int* __restrict__ klist, float* __restrict__ zwv,
    unsigned short* __restrict__ xb) {
  const int wave = threadIdx.x >> 6, l = threadIdx.x & 63;
  const int t = blockIdx.x * 4 + wave;

  float4 xr[4];
#pragma unroll
  for (int c = 0; c < 4; ++c)
    xr[c] = *(const float4*)(x + (size_t)t * HD + c * 256 + l * 4);
#pragma unroll
  for (int c = 0; c < 4; ++c) {
    ushort4 h;
    h.x = f2bf(xr[c].x); h.y = f2bf(xr[c].y); h.z = f2bf(xr[c].z); h.w = f2bf(xr[c].w);
    *(ushort4*)(xb + (size_t)t * HD + c * 256 + l * 4) = h;
  }

  float acc[NEZ];
#pragma unroll 4
  for (int e = 0; e < NEZ; ++e) {
    float4 s = {0.f, 0.f, 0.f, 0.f};
#pragma unroll
    for (int c = 0; c < 4; ++c) {
      float4 w4 = *(const float4*)(wr + (size_t)e * HD + c * 256 + l * 4);
      s.x = fmaf(w4.x, xr[c].x, s.x); s.y = fmaf(w4.y, xr[c].y, s.y);
      s.z = fmaf(w4.z, xr[c].z, s.z); s.w = fmaf(w4.w, xr[c].w, s.w);
    }
    acc[e] = (s.x + s.y) + (s.z + s.w);
  }
#pragma unroll
  for (int s = 1; s < 64; s <<= 1) {
#pragma unroll
    for (int e = 0; e < NEZ; ++e) acc[e] += __shfl_xor(acc[e], s);
  }
  float sc[NEZ], scb[NEZ];
#pragma unroll
  for (int e = 0; e < NEZ; ++e) {
    float s = 1.f / (1.f + expf(-acc[e]));
    sc[e] = s;
    scb[e] = s + bias[e];
  }
  unsigned picked = 0;
  int ids[NK]; float wv[NK]; float ssum = 0.f;
#pragma unroll
  for (int k = 0; k < NK; ++k) {
    int best = 0; float bv = -1e30f; float bsc = 0.f;
#pragma unroll
    for (int e = 0; e < NEZ; ++e) {
      bool take = (((picked >> e) & 1u) == 0) && (scb[e] > bv);
      best = take ? e : best;
      bv = take ? scb[e] : bv;
      bsc = take ? sc[e] : bsc;
    }
    picked |= 1u << best;
    ids[k] = best; wv[k] = bsc; ssum += bsc;
  }
  const float inv = SCALE_F / ssum;
  float zw = 0.f;
#pragma unroll
  for (int k = 0; k < NK; ++k)
    zw += (ids[k] >= NE) ? wv[k] * inv : 0.f;
  if (l == 0) zwv[t] = zw;
  if (l < NK) {
    int id = ids[l];
    if (id < NE) {
      int p = atomicAdd(&counts[id], 1);
      lists[id * T_TOK + p] = t;
      wlist[id * T_TOK + p] = wv[l] * inv;
      klist[id * T_TOK + p] = t * NK + l;       // output slot
    }
  }
}

// ============================ gate/up GEMM =================================
// R5-proven core. 256 thr / 4 waves (2M x 2N). Tile 128M x 64N(g,u) x 32K,
// 2-phase double buffer, 3 blocks/CU. LDS/buf 24KB:
// A[128][32]bf16 (64B pitch, slot=(c+(row>>1))&3), G,U [64][32]f32
// (128B pitch, slot=(c+row)&7).
__global__ __launch_bounds__(256, 3) void gu_k(
    const unsigned short* __restrict__ xb,
    const float* __restrict__ wg, const float* __restrict__ wu,
    const int* __restrict__ counts,
    const int* __restrict__ lists, unsigned short* __restrict__ abuf) {
  const int b = blockIdx.x;
  const int L = (b & 7) * 384 + (b >> 3);   // XCD-contiguous logical id
  const int e = L / 192;
  const int rem = L % 192;
  const int xs = rem / 16, ys = rem % 16;   // ys fastest: B-panel reuse on-XCD
  const int cnt = counts[e];
  const int m0 = ys * 128;
  if (m0 >= cnt) return;
  const int n0 = xs * 64;

  int offs_e = 0;                            // inline exclusive prefix
  for (int i = 0; i < e; ++i) offs_e += counts[i];

  __shared__ int toks[128];
  __shared__ char lds[2][24576];

  const int tid = threadIdx.x;
  if (tid < 128) {
    int m = m0 + tid;
    toks[tid] = (m < cnt) ? lists[e * T_TOK + m] : 0;
  }
  __syncthreads();

  // A: unit u=j*256+tid -> row=j*64+(tid>>2), slot p=tid&3, chunk c=(p-(row>>1))&3
  const unsigned short* asrc[2];
#pragma unroll
  for (int j = 0; j < 2; ++j) {
    int row = j * 64 + (tid >> 2);
    int c = ((tid & 3) - (row >> 1)) & 3;
    asrc[j] = xb + (size_t)toks[row] * HD + c * 8;
  }
  // B: unit u=j*256+tid -> row=j*32+(tid>>3), slot p=tid&7, chunk c=(p-row)&7
  const size_t wbase = (size_t)e * ID * HD;
  const float* gsrc[2]; const float* usrc[2];
#pragma unroll
  for (int j = 0; j < 2; ++j) {
    int row = j * 32 + (tid >> 3);
    int c = ((tid & 7) - row) & 7;
    size_t ro = wbase + (size_t)(n0 + row) * HD + c * 4;
    gsrc[j] = wg + ro; usrc[j] = wu + ro;
  }

  const int wid = tid >> 6, l = tid & 63;
  const int wm = (wid >> 1) * 64, wn = (wid & 1) * 32;
  const int q = l >> 4, r = l & 15;

  f32x4 ag[4][2] = {}; f32x4 au[4][2] = {};

  auto stage = [&](int bb, int k0) {
    char* dst = &lds[bb][0] + tid * 16;
#pragma unroll
    for (int j = 0; j < 2; ++j) {
      gload16(asrc[j] + k0, dst + j * 4096);
      gload16(gsrc[j] + k0, dst + 8192 + j * 4096);
      gload16(usrc[j] + k0, dst + 16384 + j * 4096);
    }
  };
  auto comp = [&](int bb) {
    const char* base = &lds[bb][0];
    bf16x8 a[4];
#pragma unroll
    for (int fm = 0; fm < 4; ++fm) {
      int rr = wm + fm * 16 + r;
      int p = (q + (rr >> 1)) & 3;
      a[fm] = *(const bf16x8*)(base + rr * 64 + p * 16);
    }
#pragma unroll
    for (int fn = 0; fn < 2; ++fn) {
      int cc = wn + fn * 16 + r;
      int p0 = (2 * q + cc) & 7, p1 = (2 * q + 1 + cc) & 7;
      const char* pg = base + 8192 + cc * 128;
      const char* pu = base + 16384 + cc * 128;
      float4 g0 = *(const float4*)(pg + p0 * 16);
      float4 g1 = *(const float4*)(pg + p1 * 16);
      float4 u0 = *(const float4*)(pu + p0 * 16);
      float4 u1 = *(const float4*)(pu + p1 * 16);
      bf16x8 bg = cvt8(g0, g1), bu = cvt8(u0, u1);
#pragma unroll
      for (int fm = 0; fm < 4; ++fm) {
        ag[fm][fn] = MFMA(a[fm], bg, ag[fm][fn]);
        au[fm][fn] = MFMA(a[fm], bu, au[fm][fn]);
      }
    }
  };

  stage(0, 0);
  __syncthreads();
  for (int t = 0; t < 32; t += 2) {
    stage(1, (t + 1) * 32);    // next tile in flight during compute
    comp(0);
    __syncthreads();
    if (t + 2 < 32) stage(0, (t + 2) * 32);
    comp(1);
    __syncthreads();
  }

  const int rowbase = offs_e + m0;
#pragma unroll
  for (int fm = 0; fm < 4; ++fm)
#pragma unroll
    for (int fn = 0; fn < 2; ++fn)
#pragma unroll
      for (int i2 = 0; i2 < 4; ++i2) {
        int mr = wm + fm * 16 + q * 4 + i2;       // D: row=(l>>4)*4+reg
        if (m0 + mr < cnt) {
          float g = ag[fm][fn][i2], u = au[fm][fn][i2];
          float s = 1.0f / (1.0f + expf(-g));
          float aa = g * s * u;                   // silu(g)*u
          int col = n0 + wn + fn * 16 + r;        // D: col=l&15
          abuf[(size_t)(rowbase + mr) * ID + col] = f2bf(aa);
        }
      }
}

// ============================ down GEMM ====================================
// R5-proven core. Tile 128M x 128N x 32K, 2-phase dbuf, 3 blocks/CU.
// Epilogue: plain bf16 stores to per-slot ybuf (no atomics).
__global__ __launch_bounds__(256, 3) void dn_k(
    const unsigned short* __restrict__ abuf,
    const float* __restrict__ wd,
    const int* __restrict__ counts,
    const int* __restrict__ klist, const float* __restrict__ wlist,
    unsigned short* __restrict__ ybuf) {
  const int b = blockIdx.x;
  const int L = (b & 7) * 256 + (b >> 3);
  const int e = L / 128;
  const int rem = L % 128;
  const int xs = rem / 16, ys = rem % 16;
  const int cnt = counts[e];
  const int m0 = ys * 128;
  if (m0 >= cnt) return;
  const int n0 = xs * 128;

  int offs_e = 0;
  for (int i = 0; i < e; ++i) offs_e += counts[i];

  __shared__ char lds[2][24576];

  const int tid = threadIdx.x;
  const int rowbase = offs_e + m0;

  const unsigned short* asrc[2];
#pragma unroll
  for (int j = 0; j < 2; ++j) {
    int row = j * 64 + (tid >> 2);
    int c = ((tid & 3) - (row >> 1)) & 3;
    int m = m0 + row; if (m >= cnt) m = cnt - 1;       // clamp (pad rows)
    asrc[j] = abuf + (size_t)(offs_e + m) * ID + c * 8;
  }
  const float* bsrc[4];
#pragma unroll
  for (int j = 0; j < 4; ++j) {
    int row = j * 32 + (tid >> 3);
    int c = ((tid & 7) - row) & 7;
    bsrc[j] = wd + (size_t)e * HD * ID + (size_t)(n0 + row) * ID + c * 4;
  }

  const int wid = tid >> 6, l = tid & 63;
  const int wm = (wid >> 1) * 64, wn = (wid & 1) * 64;
  const int q = l >> 4, r = l & 15;

  f32x4 acc[4][4] = {};

  auto stage = [&](int bb, int k0) {
    char* dst = &lds[bb][0] + tid * 16;
#pragma unroll
    for (int j = 0; j < 2; ++j) gload16(asrc[j] + k0, dst + j * 4096);
#pragma unroll
    for (int j = 0; j < 4; ++j) gload16(bsrc[j] + k0, dst + 8192 + j * 4096);
  };
  auto comp = [&](int bb) {
    const char* base = &lds[bb][0];
    bf16x8 a[4];
#pragma unroll
    for (int fm = 0; fm < 4; ++fm) {
      int rr = wm + fm * 16 + r;
      int p = (q + (rr >> 1)) & 3;
      a[fm] = *(const bf16x8*)(base + rr * 64 + p * 16);
    }
#pragma unroll
    for (int fn = 0; fn < 4; ++fn) {
      int cc = wn + fn * 16 + r;
      int p0 = (2 * q + cc) & 7, p1 = (2 * q + 1 + cc) & 7;
      const char* pb = base + 8192 + cc * 128;
      float4 b0 = *(const float4*)(pb + p0 * 16);
      float4 b1 = *(const float4*)(pb + p1 * 16);
      bf16x8 bb2 = cvt8(b0, b1);
#pragma unroll
      for (int fm = 0; fm < 4; ++fm)
        acc[fm][fn] = MFMA(a[fm], bb2, acc[fm][fn]);
    }
  };

  stage(0, 0);
  __syncthreads();
  for (int t = 0; t < 24; t += 2) {
    stage(1, (t + 1) * 32);
    comp(0);
    __syncthreads();
    if (t + 2 < 24) stage(0, (t + 2) * 32);
    comp(1);
    __syncthreads();
  }

#pragma unroll
  for (int fm = 0; fm < 4; ++fm) {
#pragma unroll
    for (int i2 = 0; i2 < 4; ++i2) {
      int mr = wm + fm * 16 + q * 4 + i2;
      if (m0 + mr < cnt) {
        int slot = klist[e * T_TOK + m0 + mr];         // t*4+k
        float wt = wlist[e * T_TOK + m0 + mr];
#pragma unroll
        for (int fn = 0; fn < 4; ++fn) {
          int col = n0 + wn + fn * 16 + r;
          ybuf[(size_t)slot * HD + col] = f2bf(acc[fm][fn][i2] * wt);
        }
      }
    }
  }
}

// ---------------- combine: out = x*zw + sum_k ybuf[t][k] -------------------
__global__ __launch_bounds__(256) void comb_k(
    const float* __restrict__ x, const float* __restrict__ zwv,
    const unsigned short* __restrict__ ybuf, float* __restrict__ out) {
  const int t = blockIdx.x;
  const int c = threadIdx.x;                 // 256 thr x 4 cols
  const float z = zwv[t];
  float4 xv = *(const float4*)(x + (size_t)t * HD + c * 4);
  float4 o;
  o.x = xv.x * z; o.y = xv.y * z; o.z = xv.z * z; o.w = xv.w * z;
#pragma unroll
  for (int k = 0; k < NK; ++k) {
    ushort4 yv = *(const ushort4*)(ybuf + ((size_t)(t * NK + k)) * HD + c * 4);
    o.x += bf2f(yv.x); o.y += bf2f(yv.y); o.z += bf2f(yv.z); o.w += bf2f(yv.w);
  }
  *(float4*)(out + (size_t)t * HD + c * 4) = o;
}

extern "C" void kernel_launch(void* const* d_in, const int* in_sizes, int n_in,
                              void* d_out, int out_size, void* d_ws, size_t ws_size,
                              hipStream_t stream) {
  (void)in_sizes; (void)n_in; (void)out_size; (void)ws_size;
  const float* x    = (const float*)d_in[0];
  const float* wr   = (const float*)d_in[3];
  const float* bias = (const float*)d_in[4];
  const float* wg   = (const float*)d_in[5];
  const float* wu   = (const float*)d_in[6];
  const float* wd   = (const float*)d_in[7];
  float* out = (float*)d_out;

  char* p = (char*)d_ws;
  auto alloc = [&](size_t bytes) {
    char* r = p;
    p += (bytes + 255) & ~(size_t)255;
    return r;
  };
  int*   counts  = (int*)alloc(NE * 4);
  int*   lists   = (int*)alloc((size_t)NE * T_TOK * 4);
  float* wlist   = (float*)alloc((size_t)NE * T_TOK * 4);
  int*   klist   = (int*)alloc((size_t)NE * T_TOK * 4);
  float* zwv     = (float*)alloc((size_t)T_TOK * 4);
  unsigned short* xb   = (unsigned short*)alloc((size_t)T_TOK * HD * 2);
  unsigned short* abuf = (unsigned short*)alloc((size_t)(T_TOK * NK + 128) * ID * 2);
  unsigned short* ybuf = (unsigned short*)alloc((size_t)T_TOK * NK * HD * 2);

  hipMemsetAsync(counts, 0, NE * 4, stream);
  hipMemsetAsync(ybuf, 0, (size_t)T_TOK * NK * HD * 2, stream);
  router_k<<<T_TOK / 4, 256, 0, stream>>>(x, wr, bias, counts, lists, wlist, klist, zwv, xb);
  gu_k<<<3072, 256, 0, stream>>>(xb, wg, wu, counts, lists, abuf);
  dn_k<<<2048, 256, 0, stream>>>(abuf, wd, counts, klist, wlist, ybuf);
  comb_k<<<T_TOK, 256, 0, stream>>>(x, zwv, ybuf, out);
}

// Round 12
// 127.945 us; speedup vs baseline: 1.6498x; 1.0812x over previous
//
#include <hip/hip_runtime.h>
#include <hip/hip_bf16.h>
#include <math.h>

typedef __bf16 bf16x8 __attribute__((ext_vector_type(8)));
typedef float f32x4 __attribute__((ext_vector_type(4)));

#define T_TOK 2048
#define HD 1024
#define ID 768
#define NE 16
#define NEZ 24
#define NK 4
#define SCALE_F 2.5f

#define MFMA(a, b, c) __builtin_amdgcn_mfma_f32_16x16x32_bf16(a, b, c, 0, 0, 0)

__device__ __forceinline__ unsigned short f2bf(float f) {
  unsigned int u = __builtin_bit_cast(unsigned int, f);
  u += 0x7FFFu + ((u >> 16) & 1u);          // RNE
  return (unsigned short)(u >> 16);
}

// native casts -> v_cvt_pk_bf16_f32
__device__ __forceinline__ bf16x8 cvt8(float4 a, float4 b) {
  bf16x8 t;
  t[0] = (__bf16)a.x; t[1] = (__bf16)a.y; t[2] = (__bf16)a.z; t[3] = (__bf16)a.w;
  t[4] = (__bf16)b.x; t[5] = (__bf16)b.y; t[6] = (__bf16)b.z; t[7] = (__bf16)b.w;
  return t;
}

// async global->LDS, 16B per lane; dest linear (base + lane*16)
__device__ __forceinline__ void gload16(const void* g, void* l) {
  __builtin_amdgcn_global_load_lds(
      (const __attribute__((address_space(1))) void*)(unsigned long long)(uintptr_t)g,
      (__attribute__((address_space(3))) void*)(uintptr_t)l, 16, 0, 0);
}

// ---------------- router: wave-per-token, register-only ---------------------
// Emits lists (token), wlist (weight); writes xb (bf16 x) and out = x*zw.
__global__ __launch_bounds__(256) void router_k(
    const float* __restrict__ x, const float* __restrict__ wr,
    const float* __restrict__ bias,
    int* __restrict__ counts, int* __restrict__ lists, float* __restrict__ wlist,
    unsigned short* __restrict__ xb, float* __restrict__ out) {
  const int wave = threadIdx.x >> 6, l = threadIdx.x & 63;
  const int t = blockIdx.x * 4 + wave;

  float4 xr[4];
#pragma unroll
  for (int c = 0; c < 4; ++c)
    xr[c] = *(const float4*)(x + (size_t)t * HD + c * 256 + l * 4);
#pragma unroll
  for (int c = 0; c < 4; ++c) {
    ushort4 h;
    h.x = f2bf(xr[c].x); h.y = f2bf(xr[c].y); h.z = f2bf(xr[c].z); h.w = f2bf(xr[c].w);
    *(ushort4*)(xb + (size_t)t * HD + c * 256 + l * 4) = h;
  }

  float acc[NEZ];
#pragma unroll 4
  for (int e = 0; e < NEZ; ++e) {
    float4 s = {0.f, 0.f, 0.f, 0.f};
#pragma unroll
    for (int c = 0; c < 4; ++c) {
      float4 w4 = *(const float4*)(wr + (size_t)e * HD + c * 256 + l * 4);
      s.x = fmaf(w4.x, xr[c].x, s.x); s.y = fmaf(w4.y, xr[c].y, s.y);
      s.z = fmaf(w4.z, xr[c].z, s.z); s.w = fmaf(w4.w, xr[c].w, s.w);
    }
    acc[e] = (s.x + s.y) + (s.z + s.w);
  }
#pragma unroll
  for (int s = 1; s < 64; s <<= 1) {
#pragma unroll
    for (int e = 0; e < NEZ; ++e) acc[e] += __shfl_xor(acc[e], s);
  }
  float sc[NEZ], scb[NEZ];
#pragma unroll
  for (int e = 0; e < NEZ; ++e) {
    float s = 1.f / (1.f + expf(-acc[e]));
    sc[e] = s;
    scb[e] = s + bias[e];
  }
  unsigned picked = 0;
  int ids[NK]; float wv[NK]; float ssum = 0.f;
#pragma unroll
  for (int k = 0; k < NK; ++k) {
    int best = 0; float bv = -1e30f; float bsc = 0.f;
#pragma unroll
    for (int e = 0; e < NEZ; ++e) {
      bool take = (((picked >> e) & 1u) == 0) && (scb[e] > bv);
      best = take ? e : best;
      bv = take ? scb[e] : bv;
      bsc = take ? sc[e] : bsc;
    }
    picked |= 1u << best;
    ids[k] = best; wv[k] = bsc; ssum += bsc;
  }
  const float inv = SCALE_F / ssum;
  float zw = 0.f;
#pragma unroll
  for (int k = 0; k < NK; ++k)
    zw += (ids[k] >= NE) ? wv[k] * inv : 0.f;
  if (l < NK) {
    int id = ids[l];
    if (id < NE) {
      int p = atomicAdd(&counts[id], 1);
      lists[id * T_TOK + p] = t;
      wlist[id * T_TOK + p] = wv[l] * inv;
    }
  }
#pragma unroll
  for (int c = 0; c < 4; ++c) {
    float4 o;
    o.x = xr[c].x * zw; o.y = xr[c].y * zw;
    o.z = xr[c].z * zw; o.w = xr[c].w * zw;
    *(float4*)(out + (size_t)t * HD + c * 256 + l * 4) = o;
  }
}

// ============================ gate/up GEMM =================================
// R5-proven core. 256 thr / 4 waves (2M x 2N). Tile 128M x 64N(g,u) x 32K,
// 2-phase double buffer, 3 blocks/CU. LDS/buf 24KB:
// A[128][32]bf16 (64B pitch, slot=(c+(row>>1))&3), G,U [64][32]f32
// (128B pitch, slot=(c+row)&7).
__global__ __launch_bounds__(256, 3) void gu_k(
    const unsigned short* __restrict__ xb,
    const float* __restrict__ wg, const float* __restrict__ wu,
    const int* __restrict__ counts,
    const int* __restrict__ lists, unsigned short* __restrict__ abuf) {
  const int b = blockIdx.x;
  const int L = (b & 7) * 384 + (b >> 3);   // XCD-contiguous logical id
  const int e = L / 192;
  const int rem = L % 192;
  const int xs = rem / 16, ys = rem % 16;   // ys fastest: B-panel reuse on-XCD
  const int cnt = counts[e];
  const int m0 = ys * 128;
  if (m0 >= cnt) return;
  const int n0 = xs * 64;

  int offs_e = 0;                            // inline exclusive prefix
  for (int i = 0; i < e; ++i) offs_e += counts[i];

  __shared__ int toks[128];
  __shared__ char lds[2][24576];

  const int tid = threadIdx.x;
  if (tid < 128) {
    int m = m0 + tid;
    toks[tid] = (m < cnt) ? lists[e * T_TOK + m] : 0;
  }
  __syncthreads();

  // A: unit u=j*256+tid -> row=j*64+(tid>>2), slot p=tid&3, chunk c=(p-(row>>1))&3
  const unsigned short* asrc[2];
#pragma unroll
  for (int j = 0; j < 2; ++j) {
    int row = j * 64 + (tid >> 2);
    int c = ((tid & 3) - (row >> 1)) & 3;
    asrc[j] = xb + (size_t)toks[row] * HD + c * 8;
  }
  // B: unit u=j*256+tid -> row=j*32+(tid>>3), slot p=tid&7, chunk c=(p-row)&7
  const size_t wbase = (size_t)e * ID * HD;
  const float* gsrc[2]; const float* usrc[2];
#pragma unroll
  for (int j = 0; j < 2; ++j) {
    int row = j * 32 + (tid >> 3);
    int c = ((tid & 7) - row) & 7;
    size_t ro = wbase + (size_t)(n0 + row) * HD + c * 4;
    gsrc[j] = wg + ro; usrc[j] = wu + ro;
  }

  const int wid = tid >> 6, l = tid & 63;
  const int wm = (wid >> 1) * 64, wn = (wid & 1) * 32;
  const int q = l >> 4, r = l & 15;

  f32x4 ag[4][2] = {}; f32x4 au[4][2] = {};

  auto stage = [&](int bb, int k0) {
    char* dst = &lds[bb][0] + tid * 16;
#pragma unroll
    for (int j = 0; j < 2; ++j) {
      gload16(asrc[j] + k0, dst + j * 4096);
      gload16(gsrc[j] + k0, dst + 8192 + j * 4096);
      gload16(usrc[j] + k0, dst + 16384 + j * 4096);
    }
  };
  auto comp = [&](int bb) {
    const char* base = &lds[bb][0];
    bf16x8 a[4];
#pragma unroll
    for (int fm = 0; fm < 4; ++fm) {
      int rr = wm + fm * 16 + r;
      int p = (q + (rr >> 1)) & 3;
      a[fm] = *(const bf16x8*)(base + rr * 64 + p * 16);
    }
#pragma unroll
    for (int fn = 0; fn < 2; ++fn) {
      int cc = wn + fn * 16 + r;
      int p0 = (2 * q + cc) & 7, p1 = (2 * q + 1 + cc) & 7;
      const char* pg = base + 8192 + cc * 128;
      const char* pu = base + 16384 + cc * 128;
      float4 g0 = *(const float4*)(pg + p0 * 16);
      float4 g1 = *(const float4*)(pg + p1 * 16);
      float4 u0 = *(const float4*)(pu + p0 * 16);
      float4 u1 = *(const float4*)(pu + p1 * 16);
      bf16x8 bg = cvt8(g0, g1), bu = cvt8(u0, u1);
#pragma unroll
      for (int fm = 0; fm < 4; ++fm) {
        ag[fm][fn] = MFMA(a[fm], bg, ag[fm][fn]);
        au[fm][fn] = MFMA(a[fm], bu, au[fm][fn]);
      }
    }
  };

  stage(0, 0);
  __syncthreads();
  for (int t = 0; t < 32; t += 2) {
    stage(1, (t + 1) * 32);    // next tile in flight during compute
    comp(0);
    __syncthreads();
    if (t + 2 < 32) stage(0, (t + 2) * 32);
    comp(1);
    __syncthreads();
  }

  const int rowbase = offs_e + m0;
#pragma unroll
  for (int fm = 0; fm < 4; ++fm)
#pragma unroll
    for (int fn = 0; fn < 2; ++fn)
#pragma unroll
      for (int i2 = 0; i2 < 4; ++i2) {
        int mr = wm + fm * 16 + q * 4 + i2;       // D: row=(l>>4)*4+reg
        if (m0 + mr < cnt) {
          float g = ag[fm][fn][i2], u = au[fm][fn][i2];
          float s = 1.0f / (1.0f + expf(-g));
          float aa = g * s * u;                   // silu(g)*u
          int col = n0 + wn + fn * 16 + r;        // D: col=l&15
          abuf[(size_t)(rowbase + mr) * ID + col] = f2bf(aa);
        }
      }
}

// ============================ down GEMM ====================================
// Tile 128M x 64N x 32K, 2-phase dbuf. LDS/buf 16KB: A[128][32]bf16 @0,
// B[64][32]f32 @8192. 4 blocks/CU. Grid 4096 = 8 XCD x 512, ys fastest.
// Epilogue: weighted atomicAdd into out (pre-initialized with x*zw).
__global__ __launch_bounds__(256, 4) void dn_k(
    const unsigned short* __restrict__ abuf,
    const float* __restrict__ wd,
    const int* __restrict__ counts,
    const int* __restrict__ lists, const float* __restrict__ wlist,
    float* __restrict__ out) {
  const int b = blockIdx.x;
  const int L = (b & 7) * 512 + (b >> 3);
  const int e = L / 256;
  const int rem = L % 256;
  const int xs = rem / 16, ys = rem % 16;
  const int cnt = counts[e];
  const int m0 = ys * 128;
  if (m0 >= cnt) return;
  const int n0 = xs * 64;

  int offs_e = 0;
  for (int i = 0; i < e; ++i) offs_e += counts[i];

  __shared__ char lds[2][16384];

  const int tid = threadIdx.x;

  const unsigned short* asrc[2];
#pragma unroll
  for (int j = 0; j < 2; ++j) {
    int row = j * 64 + (tid >> 2);
    int c = ((tid & 3) - (row >> 1)) & 3;
    int m = m0 + row; if (m >= cnt) m = cnt - 1;       // clamp (pad rows)
    asrc[j] = abuf + (size_t)(offs_e + m) * ID + c * 8;
  }
  const float* bsrc[2];
#pragma unroll
  for (int j = 0; j < 2; ++j) {
    int u = j * 256 + tid;
    int row = u >> 3;
    int c = ((u & 7) - row) & 7;
    bsrc[j] = wd + (size_t)e * HD * ID + (size_t)(n0 + row) * ID + c * 4;
  }

  const int wid = tid >> 6, l = tid & 63;
  const int wm = (wid >> 1) * 64, wn = (wid & 1) * 32;
  const int q = l >> 4, r = l & 15;

  f32x4 acc[4][2] = {};

  auto stage = [&](int bb, int k0) {
    char* dst = &lds[bb][0] + tid * 16;
#pragma unroll
    for (int j = 0; j < 2; ++j) {
      gload16(asrc[j] + k0, dst + j * 4096);
      gload16(bsrc[j] + k0, dst + 8192 + j * 4096);
    }
  };
  auto comp = [&](int bb) {
    const char* base = &lds[bb][0];
    bf16x8 a[4];
#pragma unroll
    for (int fm = 0; fm < 4; ++fm) {
      int rr = wm + fm * 16 + r;
      int p = (q + (rr >> 1)) & 3;
      a[fm] = *(const bf16x8*)(base + rr * 64 + p * 16);
    }
#pragma unroll
    for (int fn = 0; fn < 2; ++fn) {
      int cc = wn + fn * 16 + r;
      int p0 = (2 * q + cc) & 7, p1 = (2 * q + 1 + cc) & 7;
      const char* pb = base + 8192 + cc * 128;
      float4 b0 = *(const float4*)(pb + p0 * 16);
      float4 b1 = *(const float4*)(pb + p1 * 16);
      bf16x8 bb2 = cvt8(b0, b1);
#pragma unroll
      for (int fm = 0; fm < 4; ++fm)
        acc[fm][fn] = MFMA(a[fm], bb2, acc[fm][fn]);
    }
  };

  stage(0, 0);
  __syncthreads();
  for (int t = 0; t < 24; t += 2) {
    stage(1, (t + 1) * 32);
    comp(0);
    __syncthreads();
    if (t + 2 < 24) stage(0, (t + 2) * 32);
    comp(1);
    __syncthreads();
  }

#pragma unroll
  for (int fm = 0; fm < 4; ++fm) {
#pragma unroll
    for (int i2 = 0; i2 < 4; ++i2) {
      int mr = wm + fm * 16 + q * 4 + i2;
      if (m0 + mr < cnt) {
        int tok = lists[e * T_TOK + m0 + mr];
        float wt = wlist[e * T_TOK + m0 + mr];
#pragma unroll
        for (int fn = 0; fn < 2; ++fn) {
          int col = n0 + wn + fn * 16 + r;
          atomicAdd(&out[(size_t)tok * HD + col], acc[fm][fn][i2] * wt);
        }
      }
    }
  }
}

extern "C" void kernel_launch(void* const* d_in, const int* in_sizes, int n_in,
                              void* d_out, int out_size, void* d_ws, size_t ws_size,
                              hipStream_t stream) {
  (void)in_sizes; (void)n_in; (void)out_size; (void)ws_size;
  const float* x    = (const float*)d_in[0];
  const float* wr   = (const float*)d_in[3];
  const float* bias = (const float*)d_in[4];
  const float* wg   = (const float*)d_in[5];
  const float* wu   = (const float*)d_in[6];
  const float* wd   = (const float*)d_in[7];
  float* out = (float*)d_out;

  char* p = (char*)d_ws;
  auto alloc = [&](size_t bytes) {
    char* r = p;
    p += (bytes + 255) & ~(size_t)255;
    return r;
  };
  int*   counts  = (int*)alloc(NE * 4);
  int*   lists   = (int*)alloc((size_t)NE * T_TOK * 4);
  float* wlist   = (float*)alloc((size_t)NE * T_TOK * 4);
  unsigned short* xb   = (unsigned short*)alloc((size_t)T_TOK * HD * 2);
  unsigned short* abuf = (unsigned short*)alloc((size_t)(T_TOK * NK + 128) * ID * 2);

  hipMemsetAsync(counts, 0, NE * 4, stream);
  router_k<<<T_TOK / 4, 256, 0, stream>>>(x, wr, bias, counts, lists, wlist, xb, out);
  gu_k<<<3072, 256, 0, stream>>>(xb, wg, wu, counts, lists, abuf);
  dn_k<<<4096, 256, 0, stream>>>(abuf, wd, counts, lists, wlist, out);
}